// Round 1
// baseline (133.711 us; speedup 1.0000x reference)
//
#include <hip/hip_runtime.h>
#include <math.h>

#define BATCH 8
#define NN 512
#define EMBED 128
#define NPOS (BATCH * NN * NN)   // 2,097,152
#define PPT 8                    // positions per thread
#define BLOCK 256
#define POS_PER_BLOCK (PPT * BLOCK)   // 2048
#define NBLOCKS (NPOS / POS_PER_BLOCK) // 1024

// u = -x*log2(e) where x = pre-activation; sigmoid(x) = rcp(1 + 2^u);
// silu(x) = x*sigmoid = (-ln2 * u) * sigmoid; fold -ln2 into W2.
#define NEG_LOG2E (-1.4426950408889634f)
#define NEG_LN2   (-0.6931471805599453f)

__global__ __launch_bounds__(BLOCK) void fused_neural_bias_kernel(
    const float* __restrict__ coords,   // [B, N, 2]
    const float* __restrict__ cost,     // [B, N, N]
    const float* __restrict__ dur,      // [B, N, N]
    const float* __restrict__ W1,       // [3, E]
    const float* __restrict__ b1,       // [E]
    const float* __restrict__ W2,       // [E, 1]
    const float* __restrict__ b2,       // [1]
    float* __restrict__ out)            // [B, N, N]
{
    __shared__ float4 wpk[EMBED];   // (wa, wb, wc, b1) * -log2(e)
    __shared__ float  w2s[EMBED];   // W2 * -ln2

    const int tid = threadIdx.x;
    if (tid < EMBED) {
        float wa = W1[tid]           * NEG_LOG2E;
        float wb = W1[EMBED + tid]   * NEG_LOG2E;
        float wc = W1[2*EMBED + tid] * NEG_LOG2E;
        float bb = b1[tid]           * NEG_LOG2E;
        wpk[tid] = make_float4(wa, wb, wc, bb);
        w2s[tid] = W2[tid] * NEG_LN2;
    }
    __syncthreads();

    const float bias2 = b2[0];
    const int base = blockIdx.x * POS_PER_BLOCK + tid;

    float ang[PPT], cs[PPT], du[PPT], acc[PPT];

    const float2* c2 = (const float2*)coords;
    #pragma unroll
    for (int k = 0; k < PPT; k++) {
        int pos = base + k * BLOCK;          // coalesced per wave
        int b   = pos >> 18;                 // / (512*512)
        int rem = pos & (NN * NN - 1);
        int i   = rem >> 9;                  // / 512
        int j   = rem & (NN - 1);
        float2 ci = c2[b * NN + i];
        float2 cj = c2[b * NN + j];
        ang[k] = atan2f(ci.y - cj.y, ci.x - cj.x);
        cs[k]  = cost[pos];
        du[k]  = dur[pos];
        acc[k] = bias2;
    }

    #pragma unroll 4
    for (int e = 0; e < EMBED; e++) {
        float4 w  = wpk[e];
        float  w2 = w2s[e];
        #pragma unroll
        for (int k = 0; k < PPT; k++) {
            // u = -log2e * (angle*wa + cost*wb + dur*wc + b1)
            float u = __builtin_fmaf(ang[k], w.x,
                      __builtin_fmaf(cs[k], w.y,
                      __builtin_fmaf(du[k], w.z, w.w)));
            float p = __builtin_amdgcn_exp2f(u);          // v_exp_f32
            float r = __builtin_amdgcn_rcpf(1.0f + p);    // v_rcp_f32 = sigmoid(x)
            acc[k] = __builtin_fmaf(u * r, w2, acc[k]);   // += w2 * silu(x)
        }
    }

    #pragma unroll
    for (int k = 0; k < PPT; k++) {
        out[base + k * BLOCK] = acc[k];
    }
}

extern "C" void kernel_launch(void* const* d_in, const int* in_sizes, int n_in,
                              void* d_out, int out_size, void* d_ws, size_t ws_size,
                              hipStream_t stream) {
    const float* coords = (const float*)d_in[0];
    const float* cost   = (const float*)d_in[1];
    const float* dur    = (const float*)d_in[2];
    const float* W1     = (const float*)d_in[3];
    const float* b1     = (const float*)d_in[4];
    const float* W2     = (const float*)d_in[5];
    const float* b2     = (const float*)d_in[6];
    float* out = (float*)d_out;

    fused_neural_bias_kernel<<<NBLOCKS, BLOCK, 0, stream>>>(
        coords, cost, dur, W1, b1, W2, b2, out);
}